// Round 14
// baseline (273.253 us; speedup 1.0000x reference)
//
#include <hip/hip_runtime.h>
#include <hip/hip_bf16.h>
#include <stdint.h>

#define FDIM   1024
#define NCLS   100
#define CDIM   512
#define NBATCH 4096

typedef __attribute__((ext_vector_type(8))) short short8;
typedef __attribute__((ext_vector_type(4))) float f32x4;
typedef __attribute__((ext_vector_type(4))) int  int4v;
typedef __attribute__((ext_vector_type(8))) int  int8v;
typedef __attribute__((ext_vector_type(2))) int  int2v;

typedef const __attribute__((address_space(1))) unsigned int guint;
typedef __attribute__((address_space(3))) unsigned int luint;

__device__ __forceinline__ void gl_lds16b(const uint8_t* g, uint8_t* l) {
    __builtin_amdgcn_global_load_lds((guint*)g, (luint*)l, 16, 0, 0);
}

__device__ __forceinline__ unsigned short f2bf_bits(float f) {
    union { float f; uint32_t u; } v; v.f = f;
    uint32_t u = v.u;
    return (unsigned short)((u + 0x7FFFu + ((u >> 16) & 1u)) >> 16);
}

// ---- convert x: f32 [4096][1024] -> fp8 e4m3 (OCP, HW RNE) same layout ----
__global__ void cvt_x8(const float* __restrict__ x, uint8_t* __restrict__ xq) {
    const int i = (blockIdx.x * 256 + threadIdx.x) * 8;
    f32x4 a = *(const f32x4*)(x + i);
    f32x4 b = *(const f32x4*)(x + i + 4);
    int lo = 0, hi = 0;
    lo = __builtin_amdgcn_cvt_pk_fp8_f32(a[0], a[1], lo, false);
    lo = __builtin_amdgcn_cvt_pk_fp8_f32(a[2], a[3], lo, true);
    hi = __builtin_amdgcn_cvt_pk_fp8_f32(b[0], b[1], hi, false);
    hi = __builtin_amdgcn_cvt_pk_fp8_f32(b[2], b[3], hi, true);
    int2v v; v[0] = lo; v[1] = hi;
    *(int2v*)(xq + i) = v;
}

// ---- convert weight: f32 [m][n][j] -> fp8 [n][m][j] ----
__global__ void cvt_w8(const float* __restrict__ w, uint8_t* __restrict__ wq) {
    const int mn = blockIdx.x;              // m*NCLS + n
    const int m = mn / NCLS, n = mn % NCLS;
    const float* src = w + (size_t)mn * FDIM;
    uint8_t* dst = wq + ((size_t)n * CDIM + m) * FDIM;
    const int c = threadIdx.x * 8;
    f32x4 a = *(const f32x4*)(src + c);
    f32x4 b = *(const f32x4*)(src + c + 4);
    int lo = 0, hi = 0;
    lo = __builtin_amdgcn_cvt_pk_fp8_f32(a[0], a[1], lo, false);
    lo = __builtin_amdgcn_cvt_pk_fp8_f32(a[2], a[3], lo, true);
    hi = __builtin_amdgcn_cvt_pk_fp8_f32(b[0], b[1], hi, false);
    hi = __builtin_amdgcn_cvt_pk_fp8_f32(b[2], b[3], hi, true);
    int2v v; v[0] = lo; v[1] = hi;
    *(int2v*)(dst + c) = v;
}

// ---- fused DUQ GEMM, MX-fp8: 256 batch x 256 m-cols, BK=128, 8 K-iters ----
// r13 + WAR-hazard fix: separate af0/af1 register sets, ALL 24 ds_reads at
// iteration top. h=1's reads no longer write registers h=0's MFMAs read ->
// compiler can emit counted lgkmcnt(8) before MFMA(h0) and keep af1's reads
// in flight under the MFMA cluster (intra-wave LDS||MFMA overlap; cross-wave
// LDS service continues during other waves' MFMA). No inline asm.
__global__ __launch_bounds__(512, 2)
void duqf8(const uint8_t* __restrict__ xq, const uint8_t* __restrict__ wq,
           const float* __restrict__ csum, const float* __restrict__ cnum,
           float* __restrict__ sqp) {
    __shared__ uint8_t lsA[2][256 * 128];   // 2 x 32 KB
    __shared__ uint8_t lsB[2][256 * 128];   // 2 x 32 KB
    __shared__ float c_lds[256];
    __shared__ float red[4][256];

    const int t    = threadIdx.x;
    const int bid  = blockIdx.x;           // n*32 + rt*2 + mh
    const int n    = bid >> 5;             // class 0..99
    const int rt   = (bid >> 1) & 15;      // 256-row batch tile
    const int mh   = bid & 1;              // m half: [mh*256, +256)
    const int lane = t & 63;
    const int wid  = t >> 6;               // 0..7
    const int wm   = wid >> 2;             // 0..1 : batch rows wm*128..+127
    const int wn   = wid & 3;              // 0..3 : m cols wn*64..+63
    const int ln15 = lane & 15;
    const int kq   = lane >> 4;            // 0..3

    {   // centroids for this block's 256 m's
        const float inv = 1.0f / cnum[n];
        for (int i = t; i < 256; i += 512)
            c_lds[i] = csum[(size_t)(mh * 256 + i) * NCLS + n] * inv;
    }

    // staging: thread t covers row c*64+(t>>3), 16B at pre-swizzled col
    const int st_r = t >> 3;                       // 0..63
    const int st_c = ((t & 7) ^ (st_r & 7)) * 16;  // source byte col
    const uint8_t* gA = xq + ((size_t)(rt * 256 + st_r)) * FDIM + st_c;
    const uint8_t* gB = wq + ((size_t)(n * CDIM + mh * 256 + st_r)) * FDIM + st_c;

    auto stage = [&](int it_, int bsel_) {
        const int k_ = it_ * 128;
#pragma unroll
        for (int c = 0; c < 4; ++c) {
            gl_lds16b(gA + (size_t)(c * 64) * FDIM + k_, &lsA[bsel_][c * 8192 + t * 16]);
            gl_lds16b(gB + (size_t)(c * 64) * FDIM + k_, &lsB[bsel_][c * 8192 + t * 16]);
        }
    };

    f32x4 acc[8][4];
#pragma unroll
    for (int i = 0; i < 8; ++i)
#pragma unroll
        for (int j = 0; j < 4; ++j) acc[i][j] = f32x4{0.0f, 0.0f, 0.0f, 0.0f};

    stage(0, 0);
    __syncthreads();                 // drains gl_lds; publishes c_lds; tile 0 ready

    for (int it = 0; it < 8; ++it) {
        const int bs = it & 1;
        if (it + 1 < 8) stage(it + 1, bs ^ 1);   // other buffer; readers passed last barrier
        const uint8_t* lA = lsA[bs];
        const uint8_t* lB = lsB[bs];

        // ---- ALL fragment reads up front: bf(8), af0(8), af1(8) b128s ----
        int8v bf[4], af0[4], af1[4];
#pragma unroll
        for (int j = 0; j < 4; ++j) {
            const int row = wn * 64 + j * 16 + ln15;
            const int rsw = row & 7;
            int4v lo = *(const int4v*)(lB + row * 128 + ((kq ^ rsw) << 4));
            int4v hi = *(const int4v*)(lB + row * 128 + (((kq + 4) ^ rsw) << 4));
            union { int4v q[2]; int8v v; } u; u.q[0] = lo; u.q[1] = hi;
            bf[j] = u.v;
        }
#pragma unroll
        for (int i = 0; i < 4; ++i) {
            const int row = wm * 128 + i * 16 + ln15;
            const int rsw = row & 7;
            int4v lo = *(const int4v*)(lA + row * 128 + ((kq ^ rsw) << 4));
            int4v hi = *(const int4v*)(lA + row * 128 + (((kq + 4) ^ rsw) << 4));
            union { int4v q[2]; int8v v; } u; u.q[0] = lo; u.q[1] = hi;
            af0[i] = u.v;
        }
#pragma unroll
        for (int i = 0; i < 4; ++i) {
            const int row = wm * 128 + 64 + i * 16 + ln15;
            const int rsw = row & 7;
            int4v lo = *(const int4v*)(lA + row * 128 + ((kq ^ rsw) << 4));
            int4v hi = *(const int4v*)(lA + row * 128 + (((kq + 4) ^ rsw) << 4));
            union { int4v q[2]; int8v v; } u; u.q[0] = lo; u.q[1] = hi;
            af1[i] = u.v;
        }

        // ---- MFMA h=0 (needs bf+af0 only -> compiler emits lgkmcnt(8)) ----
        __builtin_amdgcn_s_setprio(1);
#pragma unroll
        for (int i = 0; i < 4; ++i)
#pragma unroll
            for (int j = 0; j < 4; ++j)
                acc[i][j] = __builtin_amdgcn_mfma_scale_f32_16x16x128_f8f6f4(
                    af0[i], bf[j], acc[i][j],
                    0, 0, 0, 127, 0, 127);
        // ---- MFMA h=1 (af1 reads completed under h=0's MFMA cluster) ----
#pragma unroll
        for (int i = 0; i < 4; ++i)
#pragma unroll
            for (int j = 0; j < 4; ++j)
                acc[4 + i][j] = __builtin_amdgcn_mfma_scale_f32_16x16x128_f8f6f4(
                    af1[i], bf[j], acc[4 + i][j],
                    0, 0, 0, 127, 0, 127);
        __builtin_amdgcn_s_setprio(0);
        __syncthreads();             // vmcnt drain (full compute cover) + readers done
    }

    // epilogue: (z-c)^2 over this wave's 64 m-cols, 16-lane reduce, red, sqp
    float p[8][4];
#pragma unroll
    for (int i = 0; i < 8; ++i)
#pragma unroll
        for (int r = 0; r < 4; ++r) p[i][r] = 0.0f;
#pragma unroll
    for (int i = 0; i < 8; ++i)
#pragma unroll
        for (int j = 0; j < 4; ++j) {
            const float c = c_lds[wn * 64 + j * 16 + ln15];
#pragma unroll
            for (int r = 0; r < 4; ++r) {
                const float d = acc[i][j][r] - c;
                p[i][r] += d * d;
            }
        }
#pragma unroll
    for (int i = 0; i < 8; ++i)
#pragma unroll
        for (int r = 0; r < 4; ++r) {
            float v = p[i][r];
            v += __shfl_xor(v, 1);
            v += __shfl_xor(v, 2);
            v += __shfl_xor(v, 4);
            v += __shfl_xor(v, 8);
            p[i][r] = v;
        }
    if (ln15 == 0) {
#pragma unroll
        for (int i = 0; i < 8; ++i)
#pragma unroll
            for (int r = 0; r < 4; ++r)
                red[wn][wm * 128 + i * 16 + kq * 4 + r] = p[i][r];
    }
    __syncthreads();
    if (t < 256) {       // sum the 4 wn partials -> one value per batch row
        const float s = red[0][t] + red[1][t] + red[2][t] + red[3][t];
        sqp[(size_t)mh * (NBATCH * NCLS) + (size_t)(rt * 256 + t) * NCLS + n] = s;
    }
}

// ---- finisher: sum 2 m-half partials, scale, exp ----
__global__ void finish_kernel(const float* __restrict__ sqp, float* __restrict__ out) {
    const int i = blockIdx.x * 256 + threadIdx.x;   // 0..409599
    const int NN = NBATCH * NCLS;
    const float v  = sqp[i] + sqp[NN + i];
    const float lc = v * (-50.0f / 512.0f);         // -(v/512)/(2*0.1^2)
    out[i] = expf(lc);
    out[NN + i] = lc;
}

// ---- fallback (no workspace): reg-staged inline-convert variant (r1, verified) ----
__global__ __launch_bounds__(256, 2)
void duq_fallback(const float* __restrict__ x, const float* __restrict__ w,
                  const float* __restrict__ csum, const float* __restrict__ cnum,
                  float* __restrict__ out) {
    __shared__ unsigned short lsA[128 * 64];
    __shared__ unsigned short lsB[128 * 64];
    __shared__ float c_lds[CDIM];
    __shared__ float red[2][128];

    const int t = threadIdx.x;
    const int n    = blockIdx.x >> 5;
    const int tile = blockIdx.x & 31;
    const int lane = t & 63;
    const int wid  = t >> 6;
    const int wrow = wid >> 1;
    const int wcol = wid & 1;
    const int ln15 = lane & 15;
    const int hi   = lane >> 4;

    {
        const float inv = 1.0f / cnum[n];
        for (int m = t; m < CDIM; m += 256)
            c_lds[m] = csum[(size_t)m * NCLS + n] * inv;
    }

    const int srow = t >> 3;
    const int scol = (t & 7) * 8;
    const int swz  = (srow & 7) << 4;

    float p[16];
#pragma unroll
    for (int q = 0; q < 16; ++q) p[q] = 0.0f;

    for (int chunk = 0; chunk < 4; ++chunk) {
        f32x4 acc[4][4];
#pragma unroll
        for (int i = 0; i < 4; ++i)
#pragma unroll
            for (int j = 0; j < 4; ++j)
                acc[i][j] = f32x4{0.0f, 0.0f, 0.0f, 0.0f};

        for (int ks = 0; ks < 16; ++ks) {
            const int k = ks * 64;
            __syncthreads();
#pragma unroll
            for (int pp = 0; pp < 4; ++pp) {
                const int row = pp * 32 + srow;
                const float* pa = x + ((size_t)(tile * 128 + row)) * FDIM + k + scol;
                const float* pb = w + ((size_t)(chunk * 128 + row) * NCLS + n) * FDIM + k + scol;
                f32x4 a0 = *(const f32x4*)pa, a1 = *(const f32x4*)(pa + 4);
                f32x4 b0 = *(const f32x4*)pb, b1 = *(const f32x4*)(pb + 4);
                short8 ha, hb;
#pragma unroll
                for (int e = 0; e < 4; ++e) {
                    ha[e] = (short)f2bf_bits(a0[e]); ha[e + 4] = (short)f2bf_bits(a1[e]);
                    hb[e] = (short)f2bf_bits(b0[e]); hb[e + 4] = (short)f2bf_bits(b1[e]);
                }
                const int byte = (row * 128 + scol * 2) ^ swz;
                *(short8*)((char*)lsA + byte) = ha;
                *(short8*)((char*)lsB + byte) = hb;
            }
            __syncthreads();
#pragma unroll
            for (int kk = 0; kk < 2; ++kk) {
                short8 afr[4], bfr[4];
#pragma unroll
                for (int i = 0; i < 4; ++i) {
                    const int rowA = wrow * 64 + i * 16 + ln15;
                    const int ba = (rowA * 128 + (kk * 32 + hi * 8) * 2) ^ ((rowA & 7) << 4);
                    afr[i] = *(const short8*)((const char*)lsA + ba);
                    const int rowB = wcol * 64 + i * 16 + ln15;
                    const int bb = (rowB * 128 + (kk * 32 + hi * 8) * 2) ^ ((rowB & 7) << 4);
                    bfr[i] = *(const short8*)((const char*)lsB + bb);
                }
#pragma unroll
                for (int i = 0; i < 4; ++i)
#pragma unroll
                    for (int j = 0; j < 4; ++j)
                        acc[i][j] = __builtin_amdgcn_mfma_f32_16x16x32_bf16(afr[i], bfr[j], acc[i][j], 0, 0, 0);
            }
        }

#pragma unroll
        for (int i = 0; i < 4; ++i)
#pragma unroll
            for (int j = 0; j < 4; ++j) {
                const int m = chunk * 128 + wcol * 64 + j * 16 + ln15;
                const float c = c_lds[m];
#pragma unroll
                for (int r = 0; r < 4; ++r) {
                    const float d = acc[i][j][r] - c;
                    p[i * 4 + r] += d * d;
                }
            }
    }

#pragma unroll
    for (int q = 0; q < 16; ++q) {
        float v = p[q];
        v += __shfl_xor(v, 1);
        v += __shfl_xor(v, 2);
        v += __shfl_xor(v, 4);
        v += __shfl_xor(v, 8);
        p[q] = v;
    }
    __syncthreads();
    if (ln15 == 0) {
#pragma unroll
        for (int i = 0; i < 4; ++i)
#pragma unroll
            for (int r = 0; r < 4; ++r)
                red[wcol][wrow * 64 + i * 16 + hi * 4 + r] = p[i * 4 + r];
    }
    __syncthreads();
    if (t < 128) {
        const float sq = (red[0][t] + red[1][t]) * (1.0f / 512.0f);
        const float lc = -50.0f * sq;
        const size_t b = (size_t)tile * 128 + t;
        out[b * NCLS + n] = expf(lc);
        out[(size_t)NBATCH * NCLS + b * NCLS + n] = lc;
    }
}

extern "C" void kernel_launch(void* const* d_in, const int* in_sizes, int n_in,
                              void* d_out, int out_size, void* d_ws, size_t ws_size,
                              hipStream_t stream) {
    const float* x    = (const float*)d_in[0];
    const float* w    = (const float*)d_in[1];
    const float* csum = (const float*)d_in[2];
    const float* cnum = (const float*)d_in[3];
    float* out = (float*)d_out;

    const size_t nxq = (size_t)NBATCH * FDIM;          // 4.19 MB fp8
    const size_t nwq = (size_t)CDIM * NCLS * FDIM;     // 52.4 MB fp8
    const size_t need = nxq + nwq + (size_t)2 * NBATCH * NCLS * sizeof(float);

    if (ws_size >= need) {
        uint8_t* xq = (uint8_t*)d_ws;
        uint8_t* wq = xq + nxq;
        float* sqp = (float*)(wq + nwq);
        cvt_x8<<<dim3((NBATCH * FDIM) / 2048), dim3(256), 0, stream>>>(x, xq);
        cvt_w8<<<dim3(CDIM * NCLS), dim3(128), 0, stream>>>(w, wq);
        duqf8<<<dim3(NCLS * 32), dim3(512), 0, stream>>>(xq, wq, csum, cnum, sqp);
        finish_kernel<<<dim3((NBATCH * NCLS) / 256), dim3(256), 0, stream>>>(sqp, out);
    } else {
        duq_fallback<<<dim3(NCLS * 32), dim3(256), 0, stream>>>(x, w, csum, cnum, out);
    }
}

// Round 15
// 262.012 us; speedup vs baseline: 1.0429x; 1.0429x over previous
//
#include <hip/hip_runtime.h>
#include <hip/hip_bf16.h>
#include <stdint.h>

#define FDIM   1024
#define NCLS   100
#define CDIM   512
#define NBATCH 4096

typedef __attribute__((ext_vector_type(8))) short short8;
typedef __attribute__((ext_vector_type(4))) float f32x4;
typedef __attribute__((ext_vector_type(4))) int  int4v;
typedef __attribute__((ext_vector_type(8))) int  int8v;
typedef __attribute__((ext_vector_type(2))) int  int2v;

typedef const __attribute__((address_space(1))) unsigned int guint;
typedef __attribute__((address_space(3))) unsigned int luint;

__device__ __forceinline__ void gl_lds16b(const uint8_t* g, uint8_t* l) {
    __builtin_amdgcn_global_load_lds((guint*)g, (luint*)l, 16, 0, 0);
}

__device__ __forceinline__ unsigned short f2bf_bits(float f) {
    union { float f; uint32_t u; } v; v.f = f;
    uint32_t u = v.u;
    return (unsigned short)((u + 0x7FFFu + ((u >> 16) & 1u)) >> 16);
}

// ---- convert x: f32 [4096][1024] -> fp8 e4m3 (OCP, HW RNE) same layout ----
__global__ void cvt_x8(const float* __restrict__ x, uint8_t* __restrict__ xq) {
    const int i = (blockIdx.x * 256 + threadIdx.x) * 8;
    f32x4 a = *(const f32x4*)(x + i);
    f32x4 b = *(const f32x4*)(x + i + 4);
    int lo = 0, hi = 0;
    lo = __builtin_amdgcn_cvt_pk_fp8_f32(a[0], a[1], lo, false);
    lo = __builtin_amdgcn_cvt_pk_fp8_f32(a[2], a[3], lo, true);
    hi = __builtin_amdgcn_cvt_pk_fp8_f32(b[0], b[1], hi, false);
    hi = __builtin_amdgcn_cvt_pk_fp8_f32(b[2], b[3], hi, true);
    int2v v; v[0] = lo; v[1] = hi;
    *(int2v*)(xq + i) = v;
}

// ---- convert weight: f32 [m][n][j] -> fp8 [n][m][j] ----
__global__ void cvt_w8(const float* __restrict__ w, uint8_t* __restrict__ wq) {
    const int mn = blockIdx.x;              // m*NCLS + n
    const int m = mn / NCLS, n = mn % NCLS;
    const float* src = w + (size_t)mn * FDIM;
    uint8_t* dst = wq + ((size_t)n * CDIM + m) * FDIM;
    const int c = threadIdx.x * 8;
    f32x4 a = *(const f32x4*)(src + c);
    f32x4 b = *(const f32x4*)(src + c + 4);
    int lo = 0, hi = 0;
    lo = __builtin_amdgcn_cvt_pk_fp8_f32(a[0], a[1], lo, false);
    lo = __builtin_amdgcn_cvt_pk_fp8_f32(a[2], a[3], lo, true);
    hi = __builtin_amdgcn_cvt_pk_fp8_f32(b[0], b[1], hi, false);
    hi = __builtin_amdgcn_cvt_pk_fp8_f32(b[2], b[3], hi, true);
    int2v v; v[0] = lo; v[1] = hi;
    *(int2v*)(dst + c) = v;
}

// ---- fused DUQ GEMM, MX-fp8: 256 batch x 256 m-cols, BK=128, 8 K-iters ----
// r13 (best measured: 241.6us kernel / 262.8us total). r11 structure
// (wave-tile 128x64 -> best frag economy (M+N)/2MN = 1/85) + r12's
// conflict-free chunk map (kq, kq+4): lo/hi ds_reads hit slot sets
// {0..3}^r / {4..7}^r, measured 0 conflicts. A and B share the
// (position->k) map -> correct for any HW k-order. Scales pinned 1.0.
__global__ __launch_bounds__(512, 2)
void duqf8(const uint8_t* __restrict__ xq, const uint8_t* __restrict__ wq,
           const float* __restrict__ csum, const float* __restrict__ cnum,
           float* __restrict__ sqp) {
    __shared__ uint8_t lsA[2][256 * 128];   // 2 x 32 KB
    __shared__ uint8_t lsB[2][256 * 128];   // 2 x 32 KB
    __shared__ float c_lds[256];
    __shared__ float red[4][256];

    const int t    = threadIdx.x;
    const int bid  = blockIdx.x;           // n*32 + rt*2 + mh
    const int n    = bid >> 5;             // class 0..99
    const int rt   = (bid >> 1) & 15;      // 256-row batch tile
    const int mh   = bid & 1;              // m half: [mh*256, +256)
    const int lane = t & 63;
    const int wid  = t >> 6;               // 0..7
    const int wm   = wid >> 2;             // 0..1 : batch rows wm*128..+127
    const int wn   = wid & 3;              // 0..3 : m cols wn*64..+63
    const int ln15 = lane & 15;
    const int kq   = lane >> 4;            // 0..3

    {   // centroids for this block's 256 m's
        const float inv = 1.0f / cnum[n];
        for (int i = t; i < 256; i += 512)
            c_lds[i] = csum[(size_t)(mh * 256 + i) * NCLS + n] * inv;
    }

    // staging: thread t covers row c*64+(t>>3), 16B at pre-swizzled col
    const int st_r = t >> 3;                       // 0..63
    const int st_c = ((t & 7) ^ (st_r & 7)) * 16;  // source byte col
    const uint8_t* gA = xq + ((size_t)(rt * 256 + st_r)) * FDIM + st_c;
    const uint8_t* gB = wq + ((size_t)(n * CDIM + mh * 256 + st_r)) * FDIM + st_c;

    auto stage = [&](int it_, int bsel_) {
        const int k_ = it_ * 128;
#pragma unroll
        for (int c = 0; c < 4; ++c) {
            gl_lds16b(gA + (size_t)(c * 64) * FDIM + k_, &lsA[bsel_][c * 8192 + t * 16]);
            gl_lds16b(gB + (size_t)(c * 64) * FDIM + k_, &lsB[bsel_][c * 8192 + t * 16]);
        }
    };

    f32x4 acc[8][4];
#pragma unroll
    for (int i = 0; i < 8; ++i)
#pragma unroll
        for (int j = 0; j < 4; ++j) acc[i][j] = f32x4{0.0f, 0.0f, 0.0f, 0.0f};

    stage(0, 0);
    __syncthreads();                 // drains gl_lds; publishes c_lds; tile 0 ready

    for (int it = 0; it < 8; ++it) {
        const int bs = it & 1;
        if (it + 1 < 8) stage(it + 1, bs ^ 1);   // other buffer; readers passed last barrier
        const uint8_t* lA = lsA[bs];
        const uint8_t* lB = lsB[bs];

        // B fragments: 4 col-blocks, conflict-free chunk map (kq, kq+4)
        int8v bf[4];
#pragma unroll
        for (int j = 0; j < 4; ++j) {
            const int row = wn * 64 + j * 16 + ln15;
            const int rsw = row & 7;
            int4v lo = *(const int4v*)(lB + row * 128 + ((kq ^ rsw) << 4));
            int4v hi = *(const int4v*)(lB + row * 128 + (((kq + 4) ^ rsw) << 4));
            union { int4v q[2]; int8v v; } u; u.q[0] = lo; u.q[1] = hi;
            bf[j] = u.v;
        }
#pragma unroll
        for (int h = 0; h < 2; ++h) {
            int8v af[4];
#pragma unroll
            for (int i = 0; i < 4; ++i) {
                const int row = wm * 128 + (h * 4 + i) * 16 + ln15;
                const int rsw = row & 7;
                int4v lo = *(const int4v*)(lA + row * 128 + ((kq ^ rsw) << 4));
                int4v hi = *(const int4v*)(lA + row * 128 + (((kq + 4) ^ rsw) << 4));
                union { int4v q[2]; int8v v; } u; u.q[0] = lo; u.q[1] = hi;
                af[i] = u.v;
            }
            __builtin_amdgcn_s_setprio(1);
#pragma unroll
            for (int i = 0; i < 4; ++i)
#pragma unroll
                for (int j = 0; j < 4; ++j)
                    acc[h * 4 + i][j] = __builtin_amdgcn_mfma_scale_f32_16x16x128_f8f6f4(
                        af[i], bf[j], acc[h * 4 + i][j],
                        0, 0,          // cbsz=fp8(e4m3), blgp=fp8(e4m3)
                        0, 127,        // scale A: 1.0
                        0, 127);       // scale B: 1.0
            __builtin_amdgcn_s_setprio(0);
        }
        __syncthreads();             // vmcnt drain (full compute cover) + readers done
    }

    // epilogue: (z-c)^2 over this wave's 64 m-cols, 16-lane reduce, red, sqp
    float p[8][4];
#pragma unroll
    for (int i = 0; i < 8; ++i)
#pragma unroll
        for (int r = 0; r < 4; ++r) p[i][r] = 0.0f;
#pragma unroll
    for (int i = 0; i < 8; ++i)
#pragma unroll
        for (int j = 0; j < 4; ++j) {
            const float c = c_lds[wn * 64 + j * 16 + ln15];
#pragma unroll
            for (int r = 0; r < 4; ++r) {
                const float d = acc[i][j][r] - c;
                p[i][r] += d * d;
            }
        }
#pragma unroll
    for (int i = 0; i < 8; ++i)
#pragma unroll
        for (int r = 0; r < 4; ++r) {
            float v = p[i][r];
            v += __shfl_xor(v, 1);
            v += __shfl_xor(v, 2);
            v += __shfl_xor(v, 4);
            v += __shfl_xor(v, 8);
            p[i][r] = v;
        }
    if (ln15 == 0) {
#pragma unroll
        for (int i = 0; i < 8; ++i)
#pragma unroll
            for (int r = 0; r < 4; ++r)
                red[wn][wm * 128 + i * 16 + kq * 4 + r] = p[i][r];
    }
    __syncthreads();
    if (t < 256) {       // sum the 4 wn partials -> one value per batch row
        const float s = red[0][t] + red[1][t] + red[2][t] + red[3][t];
        sqp[(size_t)mh * (NBATCH * NCLS) + (size_t)(rt * 256 + t) * NCLS + n] = s;
    }
}

// ---- finisher: sum 2 m-half partials, scale, exp ----
__global__ void finish_kernel(const float* __restrict__ sqp, float* __restrict__ out) {
    const int i = blockIdx.x * 256 + threadIdx.x;   // 0..409599
    const int NN = NBATCH * NCLS;
    const float v  = sqp[i] + sqp[NN + i];
    const float lc = v * (-50.0f / 512.0f);         // -(v/512)/(2*0.1^2)
    out[i] = expf(lc);
    out[NN + i] = lc;
}

// ---- fallback (no workspace): reg-staged inline-convert variant (r1, verified) ----
__global__ __launch_bounds__(256, 2)
void duq_fallback(const float* __restrict__ x, const float* __restrict__ w,
                  const float* __restrict__ csum, const float* __restrict__ cnum,
                  float* __restrict__ out) {
    __shared__ unsigned short lsA[128 * 64];
    __shared__ unsigned short lsB[128 * 64];
    __shared__ float c_lds[CDIM];
    __shared__ float red[2][128];

    const int t = threadIdx.x;
    const int n    = blockIdx.x >> 5;
    const int tile = blockIdx.x & 31;
    const int lane = t & 63;
    const int wid  = t >> 6;
    const int wrow = wid >> 1;
    const int wcol = wid & 1;
    const int ln15 = lane & 15;
    const int hi   = lane >> 4;

    {
        const float inv = 1.0f / cnum[n];
        for (int m = t; m < CDIM; m += 256)
            c_lds[m] = csum[(size_t)m * NCLS + n] * inv;
    }

    const int srow = t >> 3;
    const int scol = (t & 7) * 8;
    const int swz  = (srow & 7) << 4;

    float p[16];
#pragma unroll
    for (int q = 0; q < 16; ++q) p[q] = 0.0f;

    for (int chunk = 0; chunk < 4; ++chunk) {
        f32x4 acc[4][4];
#pragma unroll
        for (int i = 0; i < 4; ++i)
#pragma unroll
            for (int j = 0; j < 4; ++j)
                acc[i][j] = f32x4{0.0f, 0.0f, 0.0f, 0.0f};

        for (int ks = 0; ks < 16; ++ks) {
            const int k = ks * 64;
            __syncthreads();
#pragma unroll
            for (int pp = 0; pp < 4; ++pp) {
                const int row = pp * 32 + srow;
                const float* pa = x + ((size_t)(tile * 128 + row)) * FDIM + k + scol;
                const float* pb = w + ((size_t)(chunk * 128 + row) * NCLS + n) * FDIM + k + scol;
                f32x4 a0 = *(const f32x4*)pa, a1 = *(const f32x4*)(pa + 4);
                f32x4 b0 = *(const f32x4*)pb, b1 = *(const f32x4*)(pb + 4);
                short8 ha, hb;
#pragma unroll
                for (int e = 0; e < 4; ++e) {
                    ha[e] = (short)f2bf_bits(a0[e]); ha[e + 4] = (short)f2bf_bits(a1[e]);
                    hb[e] = (short)f2bf_bits(b0[e]); hb[e + 4] = (short)f2bf_bits(b1[e]);
                }
                const int byte = (row * 128 + scol * 2) ^ swz;
                *(short8*)((char*)lsA + byte) = ha;
                *(short8*)((char*)lsB + byte) = hb;
            }
            __syncthreads();
#pragma unroll
            for (int kk = 0; kk < 2; ++kk) {
                short8 afr[4], bfr[4];
#pragma unroll
                for (int i = 0; i < 4; ++i) {
                    const int rowA = wrow * 64 + i * 16 + ln15;
                    const int ba = (rowA * 128 + (kk * 32 + hi * 8) * 2) ^ ((rowA & 7) << 4);
                    afr[i] = *(const short8*)((const char*)lsA + ba);
                    const int rowB = wcol * 64 + i * 16 + ln15;
                    const int bb = (rowB * 128 + (kk * 32 + hi * 8) * 2) ^ ((rowB & 7) << 4);
                    bfr[i] = *(const short8*)((const char*)lsB + bb);
                }
#pragma unroll
                for (int i = 0; i < 4; ++i)
#pragma unroll
                    for (int j = 0; j < 4; ++j)
                        acc[i][j] = __builtin_amdgcn_mfma_f32_16x16x32_bf16(afr[i], bfr[j], acc[i][j], 0, 0, 0);
            }
        }

#pragma unroll
        for (int i = 0; i < 4; ++i)
#pragma unroll
            for (int j = 0; j < 4; ++j) {
                const int m = chunk * 128 + wcol * 64 + j * 16 + ln15;
                const float c = c_lds[m];
#pragma unroll
                for (int r = 0; r < 4; ++r) {
                    const float d = acc[i][j][r] - c;
                    p[i * 4 + r] += d * d;
                }
            }
    }

#pragma unroll
    for (int q = 0; q < 16; ++q) {
        float v = p[q];
        v += __shfl_xor(v, 1);
        v += __shfl_xor(v, 2);
        v += __shfl_xor(v, 4);
        v += __shfl_xor(v, 8);
        p[q] = v;
    }
    __syncthreads();
    if (ln15 == 0) {
#pragma unroll
        for (int i = 0; i < 4; ++i)
#pragma unroll
            for (int r = 0; r < 4; ++r)
                red[wcol][wrow * 64 + i * 16 + hi * 4 + r] = p[i * 4 + r];
    }
    __syncthreads();
    if (t < 128) {
        const float sq = (red[0][t] + red[1][t]) * (1.0f / 512.0f);
        const float lc = -50.0f * sq;
        const size_t b = (size_t)tile * 128 + t;
        out[b * NCLS + n] = expf(lc);
        out[(size_t)NBATCH * NCLS + b * NCLS + n] = lc;
    }
}

extern "C" void kernel_launch(void* const* d_in, const int* in_sizes, int n_in,
                              void* d_out, int out_size, void* d_ws, size_t ws_size,
                              hipStream_t stream) {
    const float* x    = (const float*)d_in[0];
    const float* w    = (const float*)d_in[1];
    const float* csum = (const float*)d_in[2];
    const float* cnum = (const float*)d_in[3];
    float* out = (float*)d_out;

    const size_t nxq = (size_t)NBATCH * FDIM;          // 4.19 MB fp8
    const size_t nwq = (size_t)CDIM * NCLS * FDIM;     // 52.4 MB fp8
    const size_t need = nxq + nwq + (size_t)2 * NBATCH * NCLS * sizeof(float);

    if (ws_size >= need) {
        uint8_t* xq = (uint8_t*)d_ws;
        uint8_t* wq = xq + nxq;
        float* sqp = (float*)(wq + nwq);
        cvt_x8<<<dim3((NBATCH * FDIM) / 2048), dim3(256), 0, stream>>>(x, xq);
        cvt_w8<<<dim3(CDIM * NCLS), dim3(128), 0, stream>>>(w, wq);
        duqf8<<<dim3(NCLS * 32), dim3(512), 0, stream>>>(xq, wq, csum, cnum, sqp);
        finish_kernel<<<dim3((NBATCH * NCLS) / 256), dim3(256), 0, stream>>>(sqp, out);
    } else {
        duq_fallback<<<dim3(NCLS * 32), dim3(256), 0, stream>>>(x, w, csum, cnum, out);
    }
}